// Round 1
// baseline (702.579 us; speedup 1.0000x reference)
//
#include <hip/hip_runtime.h>

// Problem constants
#define B_ 8
#define N_ 2048
#define T_ 12
#define F_ 64
#define CH 192      // 3 * 64 output channels
#define C_ 768      // 64 * 12 columns per diffusion GEMM

typedef __bf16 bf16x8 __attribute__((ext_vector_type(8)));
typedef float f32x4 __attribute__((ext_vector_type(4)));

__device__ __forceinline__ unsigned short f2bf(float f) {
  unsigned int u = __float_as_uint(f);
  u += 0x7FFFu + ((u >> 16) & 1u);   // RNE
  return (unsigned short)(u >> 16);
}

__device__ __forceinline__ float leaky(float v) {
  return v >= 0.0f ? v : 0.01f * v;
}

// ---------------------------------------------------------------------------
// adj fp32 -> bf16 (one float4 per thread; 8*2048*2048/4 = 8388608 threads)
// ---------------------------------------------------------------------------
__global__ __launch_bounds__(256) void convert_adj_k(const float* __restrict__ adj,
                                                     unsigned short* __restrict__ adjb) {
  size_t i = (size_t)blockIdx.x * 256 + threadIdx.x;
  const float4 v = reinterpret_cast<const float4*>(adj)[i];
  ushort4 u;
  u.x = f2bf(v.x); u.y = f2bf(v.y); u.z = f2bf(v.z); u.w = f2bf(v.w);
  reinterpret_cast<ushort4*>(adjb)[i] = u;
}

// ---------------------------------------------------------------------------
// Feature transform: for each (b, m, t) compute all 192 channels.
//   p=0 -> leaky -> out channels [0,64)
//   p=1 -> G1[b][o*12+t][m] (bf16, transposed for GEMM B^T layout)
//   p=2 -> G2 same layout
// grid (2048/256, 12, 8), block 256
// ---------------------------------------------------------------------------
__global__ __launch_bounds__(256) void transform_k(
    const float* __restrict__ x,
    const float* __restrict__ W0, const float* __restrict__ bia0,
    const float* __restrict__ W1, const float* __restrict__ bia1,
    const float* __restrict__ W2, const float* __restrict__ bia2,
    float* __restrict__ out,
    unsigned short* __restrict__ G1,
    unsigned short* __restrict__ G2)
{
  const int m = blockIdx.x * 256 + threadIdx.x;
  const int t = blockIdx.y;
  const int b = blockIdx.z;

  float xv[F_];
  {
    const size_t base = ((size_t)b * F_) * (size_t)(N_ * T_) + (size_t)m * T_ + t;
#pragma unroll
    for (int f = 0; f < F_; ++f) xv[f] = x[base + (size_t)f * (N_ * T_)];
  }

  const float* Wp[3] = {W0, W1, W2};
  const float* bp[3] = {bia0, bia1, bia2};

  for (int p = 0; p < 3; ++p) {
    const float* W = Wp[p];
    const float* bb = bp[p];
    unsigned short* G = (p == 1) ? G1 : G2;
    for (int oc = 0; oc < 64; oc += 16) {
      float acc[16];
#pragma unroll
      for (int j = 0; j < 16; ++j) acc[j] = bb[oc + j];
#pragma unroll 4
      for (int f = 0; f < F_; ++f) {
        const float xf = xv[f];
        const float* wrow = W + f * 64 + oc;
#pragma unroll
        for (int j = 0; j < 16; ++j) acc[j] = fmaf(xf, wrow[j], acc[j]);
      }
      if (p == 0) {
#pragma unroll
        for (int j = 0; j < 16; ++j)
          out[(((size_t)b * CH + (oc + j)) * N_ + m) * T_ + t] = leaky(acc[j]);
      } else {
#pragma unroll
        for (int j = 0; j < 16; ++j)
          G[((size_t)b * C_ + (size_t)(oc + j) * T_ + t) * N_ + m] = f2bf(acc[j]);
      }
    }
  }
}

// ---------------------------------------------------------------------------
// Diffusion GEMM: C[n][c] = sum_m adj[b][n][m] * Bt[b][c][m]
//   A  = adj bf16, row-major [n][m], ld 2048
//   Bt = row-major [c][m], ld 2048  (so K is unit-stride for BOTH operands)
// Tile 128x128, BK=64, 256 threads (4 waves, each 64x64 = 4x4 16x16x32 frags).
// mode 0: out[b][ochan_base + c/12][n][c%12] = leaky(C)
// mode 1: Ht[b][c][n] = bf16(C)   (transposed, feeds next diffusion)
// grid (768/128, 2048/128, 8)
// ---------------------------------------------------------------------------
#define BK 64
#define LDT 72   // 64 + 8 pad (keeps 16B alignment, breaks bank conflicts)

__global__ __launch_bounds__(256) void gemm_diff_k(
    const unsigned short* __restrict__ adjb,
    const unsigned short* __restrict__ Bt,
    float* __restrict__ out,
    unsigned short* __restrict__ Ht,
    const int mode, const int ochan_base)
{
  __shared__ __align__(16) unsigned short As[128 * LDT];
  __shared__ __align__(16) unsigned short Bs[128 * LDT];

  const int tid  = threadIdx.x;
  const int lane = tid & 63;
  const int wave = tid >> 6;
  const int wr = wave >> 1, wc = wave & 1;
  const int b  = blockIdx.z;
  const int n0 = blockIdx.y * 128;
  const int c0 = blockIdx.x * 128;

  const unsigned short* A  = adjb + (size_t)b * N_ * N_;
  const unsigned short* Bm = Bt   + (size_t)b * C_ * N_;

  f32x4 acc[4][4] = {};

  const int lrow = lane & 15;
  const int ko8  = (lane >> 4) * 8;
  const int srow = tid >> 3;        // 0..31
  const int scol = (tid & 7) * 8;   // 0..56

  for (int k0 = 0; k0 < N_; k0 += BK) {
    float4 va[4], vb[4];
#pragma unroll
    for (int p = 0; p < 4; ++p) {
      const int r = p * 32 + srow;
      va[p] = *reinterpret_cast<const float4*>(A  + (size_t)(n0 + r) * N_ + k0 + scol);
      vb[p] = *reinterpret_cast<const float4*>(Bm + (size_t)(c0 + r) * N_ + k0 + scol);
    }
#pragma unroll
    for (int p = 0; p < 4; ++p) {
      const int r = p * 32 + srow;
      *reinterpret_cast<float4*>(&As[r * LDT + scol]) = va[p];
      *reinterpret_cast<float4*>(&Bs[r * LDT + scol]) = vb[p];
    }
    __syncthreads();
#pragma unroll
    for (int kk = 0; kk < BK; kk += 32) {
      bf16x8 af[4], bfr[4];
#pragma unroll
      for (int i = 0; i < 4; ++i)
        af[i] = *reinterpret_cast<const bf16x8*>(&As[(wr * 64 + i * 16 + lrow) * LDT + kk + ko8]);
#pragma unroll
      for (int j = 0; j < 4; ++j)
        bfr[j] = *reinterpret_cast<const bf16x8*>(&Bs[(wc * 64 + j * 16 + lrow) * LDT + kk + ko8]);
#pragma unroll
      for (int i = 0; i < 4; ++i)
#pragma unroll
        for (int j = 0; j < 4; ++j)
          acc[i][j] = __builtin_amdgcn_mfma_f32_16x16x32_bf16(af[i], bfr[j], acc[i][j], 0, 0, 0);
    }
    __syncthreads();
  }

  // Epilogue. C/D frag layout (verified m89): col = lane&15, row = (lane>>4)*4 + reg
  const int r4 = (lane >> 4) * 4;
  if (mode == 0) {
    float* outb = out + (size_t)b * CH * N_ * T_;
#pragma unroll
    for (int i = 0; i < 4; ++i) {
#pragma unroll
      for (int j = 0; j < 4; ++j) {
        const int c = c0 + wc * 64 + j * 16 + lrow;
        const int o = c / 12;
        const int t = c - o * 12;
#pragma unroll
        for (int r = 0; r < 4; ++r) {
          const int n = n0 + wr * 64 + i * 16 + r4 + r;
          outb[((size_t)(ochan_base + o) * N_ + n) * T_ + t] = leaky(acc[i][j][r]);
        }
      }
    }
  } else {
    unsigned short* Hb = Ht + (size_t)b * C_ * N_;
#pragma unroll
    for (int i = 0; i < 4; ++i) {
#pragma unroll
      for (int j = 0; j < 4; ++j) {
        const int c = c0 + wc * 64 + j * 16 + lrow;
#pragma unroll
        for (int r = 0; r < 4; ++r) {
          const int n = n0 + wr * 64 + i * 16 + r4 + r;
          Hb[(size_t)c * N_ + n] = f2bf(acc[i][j][r]);
        }
      }
    }
  }
}

// ---------------------------------------------------------------------------
// Workspace layout (bytes):
//   adjb : [0, 67108864)                 8*2048*2048 bf16
//   G1   : [67108864, 92274688)          8*768*2048 bf16   (also reused as Ht)
//   G2   : [92274688, 117440512)         8*768*2048 bf16
// Total required: 117,440,512 B
// ---------------------------------------------------------------------------
extern "C" void kernel_launch(void* const* d_in, const int* in_sizes, int n_in,
                              void* d_out, int out_size, void* d_ws, size_t ws_size,
                              hipStream_t stream) {
  const float* x   = (const float*)d_in[0];
  const float* adj = (const float*)d_in[1];
  const float* W0  = (const float*)d_in[2];
  const float* b0  = (const float*)d_in[3];
  const float* W1  = (const float*)d_in[4];
  const float* b1  = (const float*)d_in[5];
  const float* W2  = (const float*)d_in[6];
  const float* b2  = (const float*)d_in[7];
  float* out = (float*)d_out;

  char* ws = (char*)d_ws;
  unsigned short* adjb = (unsigned short*)ws;
  unsigned short* G1   = (unsigned short*)(ws + 67108864);
  unsigned short* G2   = (unsigned short*)(ws + 92274688);
  unsigned short* Ht   = G1;  // G1 is dead after diffusion pass 1 -> reuse

  // 1) adj -> bf16
  hipLaunchKernelGGL(convert_adj_k, dim3((B_ * N_ * N_ / 4) / 256), dim3(256), 0, stream,
                     adj, adjb);

  // 2) feature transform (p=0 straight to out; G1/G2 staged transposed bf16)
  hipLaunchKernelGGL(transform_k, dim3(N_ / 256, T_, B_), dim3(256), 0, stream,
                     x, W0, b0, W1, b1, W2, b2, out, G1, G2);

  // 3) diffusion p=1: out[64:128] = leaky(adj @ G1)
  hipLaunchKernelGGL(gemm_diff_k, dim3(C_ / 128, N_ / 128, B_), dim3(256), 0, stream,
                     adjb, G1, out, (unsigned short*)nullptr, 0, 64);

  // 4) diffusion p=2 hop 1: Ht = bf16(adj @ G2), transposed
  hipLaunchKernelGGL(gemm_diff_k, dim3(C_ / 128, N_ / 128, B_), dim3(256), 0, stream,
                     adjb, G2, out, Ht, 1, 0);

  // 5) diffusion p=2 hop 2: out[128:192] = leaky(adj @ Ht)
  hipLaunchKernelGGL(gemm_diff_k, dim3(C_ / 128, N_ / 128, B_), dim3(256), 0, stream,
                     adjb, Ht, out, (unsigned short*)nullptr, 0, 128);
}

// Round 2
// 392.575 us; speedup vs baseline: 1.7897x; 1.7897x over previous
//
#include <hip/hip_runtime.h>

// Problem constants
#define B_ 8
#define N_ 2048
#define T_ 12
#define F_ 64
#define NT 24576    // N_*T_
#define CH 192      // 3 * 64 output channels
#define C_ 768      // 64 * 12 rows per diffusion GEMM B-operand

typedef __bf16 bf16x8 __attribute__((ext_vector_type(8)));
typedef float f32x4 __attribute__((ext_vector_type(4)));

typedef const __attribute__((address_space(1))) unsigned int as1_uint;
typedef __attribute__((address_space(3))) unsigned int as3_uint;

__device__ __forceinline__ void gload16(const void* g, void* l) {
  __builtin_amdgcn_global_load_lds((as1_uint*)g, (as3_uint*)l, 16, 0, 0);
}

__device__ __forceinline__ unsigned short f2bf(float f) {
  unsigned int u = __float_as_uint(f);
  u += 0x7FFFu + ((u >> 16) & 1u);   // RNE
  return (unsigned short)(u >> 16);
}

__device__ __forceinline__ float leaky(float v) {
  return v >= 0.0f ? v : 0.01f * v;
}

// ---------------------------------------------------------------------------
// adj fp32 -> bf16
// ---------------------------------------------------------------------------
__global__ __launch_bounds__(256) void convert_adj_k(const float* __restrict__ adj,
                                                     unsigned short* __restrict__ adjb) {
  size_t i = (size_t)blockIdx.x * 256 + threadIdx.x;
  const float4 v = reinterpret_cast<const float4*>(adj)[i];
  ushort4 u;
  u.x = f2bf(v.x); u.y = f2bf(v.y); u.z = f2bf(v.z); u.w = f2bf(v.w);
  reinterpret_cast<ushort4*>(adjb)[i] = u;
}

// ---------------------------------------------------------------------------
// Stage W^T (bf16, padded rows of 72) + bias into LDS. W is [64 f][64 o].
// Wt[o][f]. 256 threads.
// ---------------------------------------------------------------------------
__device__ __forceinline__ void stage_wt(const float* __restrict__ W,
                                         unsigned short* Wt, int tid) {
  const int f = tid >> 2;
  const int q = tid & 3;
  const float4* row = reinterpret_cast<const float4*>(W + f * 64 + q * 16);
#pragma unroll
  for (int v4 = 0; v4 < 4; ++v4) {
    float4 v = row[v4];
    const int ob = q * 16 + v4 * 4;
    Wt[(ob + 0) * 72 + f] = f2bf(v.x);
    Wt[(ob + 1) * 72 + f] = f2bf(v.y);
    Wt[(ob + 2) * 72 + f] = f2bf(v.z);
    Wt[(ob + 3) * 72 + f] = f2bf(v.w);
  }
}

// ---------------------------------------------------------------------------
// p0_k: out[:, 0:64] = leaky(x . W0 + b0)   via MFMA, linear-e mapping.
// A = W0^T (rows o, k=f), B = x (cols e, k=f). D: col=lane&15=e, row=o.
// grid (NT/64, B_), block 256 (4 waves x 16 e each)
// ---------------------------------------------------------------------------
__global__ __launch_bounds__(256) void p0_k(const float* __restrict__ x,
                                            const float* __restrict__ W0,
                                            const float* __restrict__ bia0,
                                            float* __restrict__ out) {
  __shared__ unsigned short Wt[64 * 72];
  __shared__ float bias[64];
  const int tid = threadIdx.x;
  stage_wt(W0, Wt, tid);
  if (tid < 64) bias[tid] = bia0[tid];
  __syncthreads();

  const int lane = tid & 63;
  const int wave = tid >> 6;
  const int b = blockIdx.y;
  const int e = blockIdx.x * 64 + wave * 16 + (lane & 15);
  const int fgrp = (lane >> 4) * 8;
  const float* xb = x + (size_t)b * F_ * NT;

  bf16x8 xf[2];
#pragma unroll
  for (int kf = 0; kf < 2; ++kf)
#pragma unroll
    for (int j = 0; j < 8; ++j)
      xf[kf][j] = (__bf16)xb[(size_t)(fgrp + kf * 32 + j) * NT + e];

  float* outb = out + (size_t)b * CH * NT;
#pragma unroll
  for (int ob = 0; ob < 4; ++ob) {
    f32x4 acc = {};
#pragma unroll
    for (int kf = 0; kf < 2; ++kf) {
      bf16x8 af = *reinterpret_cast<const bf16x8*>(
          &Wt[(ob * 16 + (lane & 15)) * 72 + kf * 32 + fgrp]);
      acc = __builtin_amdgcn_mfma_f32_16x16x32_bf16(af, xf[kf], acc, 0, 0, 0);
    }
#pragma unroll
    for (int r = 0; r < 4; ++r) {
      const int o = ob * 16 + (lane >> 4) * 4 + r;
      outb[(size_t)o * NT + e] = leaky(acc[r] + bias[o]);
    }
  }
}

// ---------------------------------------------------------------------------
// p12_k: G1 = x.W1 + b1, G2 = x.W2 + b2 (no activation), written bf16 to
// G_p[(o*12+t)*N_ + n]  (rows=channel-time, cols=node: K-contig for GEMM).
// Block covers 16 nodes x all 12 t (every x line fully consumed in-block).
// Wave w handles t = w*3 .. w*3+2; e-tile = 16 consecutive n at fixed t.
// grid (N_/16, B_), block 256.
// ---------------------------------------------------------------------------
__global__ __launch_bounds__(256) void p12_k(const float* __restrict__ x,
                                             const float* __restrict__ W1,
                                             const float* __restrict__ bia1,
                                             const float* __restrict__ W2,
                                             const float* __restrict__ bia2,
                                             unsigned short* __restrict__ G1,
                                             unsigned short* __restrict__ G2) {
  __shared__ unsigned short Wt[2][64 * 72];
  __shared__ float bias[2][64];
  const int tid = threadIdx.x;
  stage_wt(W1, Wt[0], tid);
  stage_wt(W2, Wt[1], tid);
  if (tid < 64) bias[0][tid] = bia1[tid];
  else if (tid < 128) bias[1][tid - 64] = bia2[tid - 64];
  __syncthreads();

  const int lane = tid & 63;
  const int wave = tid >> 6;
  const int b = blockIdx.y;
  const int n0 = blockIdx.x * 16;
  const int n = n0 + (lane & 15);
  const int fgrp = (lane >> 4) * 8;
  const float* xb = x + (size_t)b * F_ * NT;
  unsigned short* Gp[2] = {G1 + (size_t)b * C_ * N_, G2 + (size_t)b * C_ * N_};

#pragma unroll
  for (int it = 0; it < 3; ++it) {
    const int t = wave * 3 + it;
    const int e = n * T_ + t;

    bf16x8 xf[2];
#pragma unroll
    for (int kf = 0; kf < 2; ++kf)
#pragma unroll
      for (int j = 0; j < 8; ++j)
        xf[kf][j] = (__bf16)xb[(size_t)(fgrp + kf * 32 + j) * NT + e];

#pragma unroll
    for (int p = 0; p < 2; ++p) {
#pragma unroll
      for (int ob = 0; ob < 4; ++ob) {
        f32x4 acc = {};
#pragma unroll
        for (int kf = 0; kf < 2; ++kf) {
          bf16x8 af = *reinterpret_cast<const bf16x8*>(
              &Wt[p][(ob * 16 + (lane & 15)) * 72 + kf * 32 + fgrp]);
          acc = __builtin_amdgcn_mfma_f32_16x16x32_bf16(af, xf[kf], acc, 0, 0, 0);
        }
#pragma unroll
        for (int r = 0; r < 4; ++r) {
          const int o = ob * 16 + (lane >> 4) * 4 + r;
          Gp[p][(size_t)(o * T_ + t) * N_ + n] = f2bf(acc[r] + bias[p][o]);
        }
      }
    }
  }
}

// ---------------------------------------------------------------------------
// Diffusion GEMM: C[n][c] = sum_m adj[b][n][m] * Bt[b][c][m]
// Staging via global_load_lds width 16 into linear LDS (m97 structure).
// Tile 128x128, BK=64, 256 threads, 4 waves, 4x4 16x16x32 frags each.
// mode 0: out[b][ochan_base + c/12][n][c%12] = leaky(C)
// mode 1: Ht[b][c][n] = bf16(C)
// grid (C_/128, N_/128, B_)
// ---------------------------------------------------------------------------
#define BK 64

__global__ __launch_bounds__(256) void gemm_diff_k(
    const unsigned short* __restrict__ adjb,
    const unsigned short* __restrict__ Bt,
    float* __restrict__ out,
    unsigned short* __restrict__ Ht,
    const int mode, const int ochan_base)
{
  __shared__ __align__(16) unsigned short As[128 * BK];
  __shared__ __align__(16) unsigned short Bs[128 * BK];

  const int tid  = threadIdx.x;
  const int lane = tid & 63;
  const int wave = tid >> 6;
  const int wr = wave >> 1, wc = wave & 1;
  const int b  = blockIdx.z;
  const int n0 = blockIdx.y * 128;
  const int c0 = blockIdx.x * 128;

  const unsigned short* A  = adjb + (size_t)b * N_ * N_;
  const unsigned short* Bm = Bt   + (size_t)b * C_ * N_;

  f32x4 acc[4][4] = {};

  const int lrow = lane & 15;
  const int ko8  = (lane >> 4) * 8;
  const int strow = wave * 8 + (lane >> 3);  // staged row within 32-row round
  const int stcol = (lane & 7) * 8;          // staged col (8 bf16 = 16B)

  for (int k0 = 0; k0 < N_; k0 += BK) {
#pragma unroll
    for (int r = 0; r < 4; ++r) {
      gload16(A  + (size_t)(n0 + r * 32 + strow) * N_ + k0 + stcol,
              As + r * 2048 + wave * 512);
      gload16(Bm + (size_t)(c0 + r * 32 + strow) * N_ + k0 + stcol,
              Bs + r * 2048 + wave * 512);
    }
    __syncthreads();
#pragma unroll
    for (int kk = 0; kk < BK; kk += 32) {
      bf16x8 af[4], bfr[4];
#pragma unroll
      for (int i = 0; i < 4; ++i)
        af[i] = *reinterpret_cast<const bf16x8*>(&As[(wr * 64 + i * 16 + lrow) * BK + kk + ko8]);
#pragma unroll
      for (int j = 0; j < 4; ++j)
        bfr[j] = *reinterpret_cast<const bf16x8*>(&Bs[(wc * 64 + j * 16 + lrow) * BK + kk + ko8]);
#pragma unroll
      for (int i = 0; i < 4; ++i)
#pragma unroll
        for (int j = 0; j < 4; ++j)
          acc[i][j] = __builtin_amdgcn_mfma_f32_16x16x32_bf16(af[i], bfr[j], acc[i][j], 0, 0, 0);
    }
    __syncthreads();
  }

  // Epilogue. D layout: col = lane&15 (c), row = (lane>>4)*4 + reg (n)
  const int r4 = (lane >> 4) * 4;
  if (mode == 0) {
    float* outb = out + (size_t)b * CH * N_ * T_;
#pragma unroll
    for (int i = 0; i < 4; ++i) {
#pragma unroll
      for (int j = 0; j < 4; ++j) {
        const int c = c0 + wc * 64 + j * 16 + lrow;
        const int o = c / 12;
        const int t = c - o * 12;
#pragma unroll
        for (int r = 0; r < 4; ++r) {
          const int n = n0 + wr * 64 + i * 16 + r4 + r;
          outb[((size_t)(ochan_base + o) * N_ + n) * T_ + t] = leaky(acc[i][j][r]);
        }
      }
    }
  } else {
    unsigned short* Hb = Ht + (size_t)b * C_ * N_;
#pragma unroll
    for (int i = 0; i < 4; ++i) {
#pragma unroll
      for (int j = 0; j < 4; ++j) {
        const int c = c0 + wc * 64 + j * 16 + lrow;
        const int nb = n0 + wr * 64 + i * 16 + r4;
        ushort4 u;
        u.x = f2bf(acc[i][j][0]);
        u.y = f2bf(acc[i][j][1]);
        u.z = f2bf(acc[i][j][2]);
        u.w = f2bf(acc[i][j][3]);
        *reinterpret_cast<ushort4*>(&Hb[(size_t)c * N_ + nb]) = u;
      }
    }
  }
}

// ---------------------------------------------------------------------------
// Workspace layout (bytes):
//   adjb : [0, 67108864)                 8*2048*2048 bf16
//   G1   : [67108864, 92274688)          8*768*2048 bf16   (reused as Ht)
//   G2   : [92274688, 117440512)         8*768*2048 bf16
// ---------------------------------------------------------------------------
extern "C" void kernel_launch(void* const* d_in, const int* in_sizes, int n_in,
                              void* d_out, int out_size, void* d_ws, size_t ws_size,
                              hipStream_t stream) {
  const float* x   = (const float*)d_in[0];
  const float* adj = (const float*)d_in[1];
  const float* W0  = (const float*)d_in[2];
  const float* b0  = (const float*)d_in[3];
  const float* W1  = (const float*)d_in[4];
  const float* b1  = (const float*)d_in[5];
  const float* W2  = (const float*)d_in[6];
  const float* b2  = (const float*)d_in[7];
  float* out = (float*)d_out;

  char* ws = (char*)d_ws;
  unsigned short* adjb = (unsigned short*)ws;
  unsigned short* G1   = (unsigned short*)(ws + 67108864);
  unsigned short* G2   = (unsigned short*)(ws + 92274688);
  unsigned short* Ht   = G1;  // G1 dead after diffusion pass 1 -> reuse

  // 1) adj -> bf16
  hipLaunchKernelGGL(convert_adj_k, dim3((B_ * N_ * N_ / 4) / 256), dim3(256), 0, stream,
                     adj, adjb);

  // 2) p=0: out channels [0,64) directly
  hipLaunchKernelGGL(p0_k, dim3(NT / 64, B_), dim3(256), 0, stream,
                     x, W0, b0, out);

  // 3) p=1,2 feature transforms -> G1, G2 (bf16, [c][m] layout)
  hipLaunchKernelGGL(p12_k, dim3(N_ / 16, B_), dim3(256), 0, stream,
                     x, W1, b1, W2, b2, G1, G2);

  // 4) diffusion p=1: out[64:128] = leaky(adj @ G1)
  hipLaunchKernelGGL(gemm_diff_k, dim3(C_ / 128, N_ / 128, B_), dim3(256), 0, stream,
                     adjb, G1, out, (unsigned short*)nullptr, 0, 64);

  // 5) diffusion p=2 hop 1: Ht = bf16(adj @ G2)
  hipLaunchKernelGGL(gemm_diff_k, dim3(C_ / 128, N_ / 128, B_), dim3(256), 0, stream,
                     adjb, G2, out, Ht, 1, 0);

  // 6) diffusion p=2 hop 2: out[128:192] = leaky(adj @ Ht)
  hipLaunchKernelGGL(gemm_diff_k, dim3(C_ / 128, N_ / 128, B_), dim3(256), 0, stream,
                     adjb, Ht, out, (unsigned short*)nullptr, 0, 128);
}

// Round 3
// 293.383 us; speedup vs baseline: 2.3948x; 1.3381x over previous
//
#include <hip/hip_runtime.h>

// Problem constants
#define B_ 8
#define N_ 2048
#define T_ 12
#define F_ 64
#define NT 24576    // N_*T_
#define CH 192      // 3 * 64 output channels
#define C_ 768      // 64 * 12 rows per diffusion GEMM B-operand

typedef __bf16 bf16x8 __attribute__((ext_vector_type(8)));
typedef float f32x4 __attribute__((ext_vector_type(4)));

typedef const __attribute__((address_space(1))) unsigned int as1_uint;
typedef __attribute__((address_space(3))) unsigned int as3_uint;

__device__ __forceinline__ void gload16(const void* g, void* l) {
  __builtin_amdgcn_global_load_lds((as1_uint*)g, (as3_uint*)l, 16, 0, 0);
}

__device__ __forceinline__ unsigned short f2bf(float f) {
  unsigned int u = __float_as_uint(f);
  u += 0x7FFFu + ((u >> 16) & 1u);   // RNE
  return (unsigned short)(u >> 16);
}

__device__ __forceinline__ float leaky(float v) {
  return v >= 0.0f ? v : 0.01f * v;
}

// ---------------------------------------------------------------------------
// adj fp32 -> bf16
// ---------------------------------------------------------------------------
__global__ __launch_bounds__(256) void convert_adj_k(const float* __restrict__ adj,
                                                     unsigned short* __restrict__ adjb) {
  size_t i = (size_t)blockIdx.x * 256 + threadIdx.x;
  const float4 v = reinterpret_cast<const float4*>(adj)[i];
  ushort4 u;
  u.x = f2bf(v.x); u.y = f2bf(v.y); u.z = f2bf(v.z); u.w = f2bf(v.w);
  reinterpret_cast<ushort4*>(adjb)[i] = u;
}

// ---------------------------------------------------------------------------
// Stage W^T (bf16, padded rows of 72) + bias into LDS. W is [64 f][64 o].
// ---------------------------------------------------------------------------
__device__ __forceinline__ void stage_wt(const float* __restrict__ W,
                                         unsigned short* Wt, int tid) {
  const int f = tid >> 2;
  const int q = tid & 3;
  const float4* row = reinterpret_cast<const float4*>(W + f * 64 + q * 16);
#pragma unroll
  for (int v4 = 0; v4 < 4; ++v4) {
    float4 v = row[v4];
    const int ob = q * 16 + v4 * 4;
    Wt[(ob + 0) * 72 + f] = f2bf(v.x);
    Wt[(ob + 1) * 72 + f] = f2bf(v.y);
    Wt[(ob + 2) * 72 + f] = f2bf(v.z);
    Wt[(ob + 3) * 72 + f] = f2bf(v.w);
  }
}

// ---------------------------------------------------------------------------
// p0_k: out[:, 0:64] = leaky(x . W0 + b0)   via MFMA, linear-e mapping.
// ---------------------------------------------------------------------------
__global__ __launch_bounds__(256) void p0_k(const float* __restrict__ x,
                                            const float* __restrict__ W0,
                                            const float* __restrict__ bia0,
                                            float* __restrict__ out) {
  __shared__ unsigned short Wt[64 * 72];
  __shared__ float bias[64];
  const int tid = threadIdx.x;
  stage_wt(W0, Wt, tid);
  if (tid < 64) bias[tid] = bia0[tid];
  __syncthreads();

  const int lane = tid & 63;
  const int wave = tid >> 6;
  const int b = blockIdx.y;
  const int e = blockIdx.x * 64 + wave * 16 + (lane & 15);
  const int fgrp = (lane >> 4) * 8;
  const float* xb = x + (size_t)b * F_ * NT;

  bf16x8 xf[2];
#pragma unroll
  for (int kf = 0; kf < 2; ++kf)
#pragma unroll
    for (int j = 0; j < 8; ++j)
      xf[kf][j] = (__bf16)xb[(size_t)(fgrp + kf * 32 + j) * NT + e];

  float* outb = out + (size_t)b * CH * NT;
#pragma unroll
  for (int ob = 0; ob < 4; ++ob) {
    f32x4 acc = {};
#pragma unroll
    for (int kf = 0; kf < 2; ++kf) {
      bf16x8 af = *reinterpret_cast<const bf16x8*>(
          &Wt[(ob * 16 + (lane & 15)) * 72 + kf * 32 + fgrp]);
      acc = __builtin_amdgcn_mfma_f32_16x16x32_bf16(af, xf[kf], acc, 0, 0, 0);
    }
#pragma unroll
    for (int r = 0; r < 4; ++r) {
      const int o = ob * 16 + (lane >> 4) * 4 + r;
      outb[(size_t)o * NT + e] = leaky(acc[r] + bias[o]);
    }
  }
}

// ---------------------------------------------------------------------------
// p12_k: G1 = x.W1 + b1, G2 = x.W2 + b2 (no activation), bf16 to
// G_p[(o*12+t)*N_ + n]  (K-contig for GEMM).
// ---------------------------------------------------------------------------
__global__ __launch_bounds__(256) void p12_k(const float* __restrict__ x,
                                             const float* __restrict__ W1,
                                             const float* __restrict__ bia1,
                                             const float* __restrict__ W2,
                                             const float* __restrict__ bia2,
                                             unsigned short* __restrict__ G1,
                                             unsigned short* __restrict__ G2) {
  __shared__ unsigned short Wt[2][64 * 72];
  __shared__ float bias[2][64];
  const int tid = threadIdx.x;
  stage_wt(W1, Wt[0], tid);
  stage_wt(W2, Wt[1], tid);
  if (tid < 64) bias[0][tid] = bia1[tid];
  else if (tid < 128) bias[1][tid - 64] = bia2[tid - 64];
  __syncthreads();

  const int lane = tid & 63;
  const int wave = tid >> 6;
  const int b = blockIdx.y;
  const int n = blockIdx.x * 16 + (lane & 15);
  const int fgrp = (lane >> 4) * 8;
  const float* xb = x + (size_t)b * F_ * NT;
  unsigned short* Gp[2] = {G1 + (size_t)b * C_ * N_, G2 + (size_t)b * C_ * N_};

#pragma unroll
  for (int it = 0; it < 3; ++it) {
    const int t = wave * 3 + it;
    const int e = n * T_ + t;

    bf16x8 xf[2];
#pragma unroll
    for (int kf = 0; kf < 2; ++kf)
#pragma unroll
      for (int j = 0; j < 8; ++j)
        xf[kf][j] = (__bf16)xb[(size_t)(fgrp + kf * 32 + j) * NT + e];

#pragma unroll
    for (int p = 0; p < 2; ++p) {
#pragma unroll
      for (int ob = 0; ob < 4; ++ob) {
        f32x4 acc = {};
#pragma unroll
        for (int kf = 0; kf < 2; ++kf) {
          bf16x8 af = *reinterpret_cast<const bf16x8*>(
              &Wt[p][(ob * 16 + (lane & 15)) * 72 + kf * 32 + fgrp]);
          acc = __builtin_amdgcn_mfma_f32_16x16x32_bf16(af, xf[kf], acc, 0, 0, 0);
        }
#pragma unroll
        for (int r = 0; r < 4; ++r) {
          const int o = ob * 16 + (lane >> 4) * 4 + r;
          Gp[p][(size_t)(o * T_ + t) * N_ + n] = f2bf(acc[r] + bias[p][o]);
        }
      }
    }
  }
}

// ---------------------------------------------------------------------------
// 256x256 8-phase diffusion GEMM (T2+T3+T4+T5 per learn_hip m201 template).
// C[n][c] = sum_m adj[b][n][m] * Bt[b][c][m],  K = 2048, BK = 64.
// 512 threads = 8 waves (2 M x 4 N), per-wave output 128x64, acc[8][4].
// LDS 128KB: per K-tile buffer, A and B stored as [2 kh][256 rows][32 cols]
// bf16 (row stride 64B -> conflict-free 16-row ds_read_b128; each kh-plane is
// a contiguous 16KB region -> linear global_load_lds, no swizzle needed).
// Even K-tiles live in buf0, odd in buf1. Each phase computes one (kh, qm)
// quadrant (16 MFMA) and stages one half-plane 4-6 phases ahead:
//   gp0: A(2i+1)kh1   gp1: B(2i+1)kh1 +vmcnt(8)
//   gp2: A(2i+2)kh0   gp3: B(2i+2)kh0 +vmcnt(8)
//   gp4: A(2i+2)kh1   gp5: B(2i+2)kh1 +vmcnt(8)
//   gp6: A(2i+3)kh0   gp7: B(2i+3)kh0 +vmcnt(8)
// vmcnt(8) = 4 half-planes in flight; never 0 in steady state.
// grid 192 = 8 batches x (8 n-tiles x 3 c-tiles); blockIdx&7 = batch = XCD.
// ---------------------------------------------------------------------------
__global__ __launch_bounds__(512, 2) void gemm8_k(
    const unsigned short* __restrict__ adjb,
    const unsigned short* __restrict__ Bt,
    float* __restrict__ out,
    unsigned short* __restrict__ Ht,
    const int mode, const int ochan_base)
{
  extern __shared__ __align__(16) unsigned short lds[];  // 65536 shorts = 128KB
  // layout (shorts): A buf0 @0, A buf1 @16384, B buf0 @32768, B buf1 @49152
  // within buf: kh*8192 + row*32 + col

  const int tid  = threadIdx.x;
  const int lane = tid & 63;
  const int wave = tid >> 6;
  const int wr = wave >> 2;      // 0..1  (M half)
  const int wc = wave & 3;       // 0..3  (N quarter)

  const int b     = blockIdx.x & 7;          // batch == XCD (round-robin)
  const int w     = blockIdx.x >> 3;         // 0..23
  const int n0    = (w & 7) * 256;
  const int c0    = (w >> 3) * 256;

  const unsigned short* A  = adjb + (size_t)b * N_ * N_;
  const unsigned short* Bm = Bt   + (size_t)b * C_ * N_;

  // per-lane global staging bases: lane covers row (lane>>2), col (lane&3)*8
  const unsigned short* aSt = A  + (size_t)(n0 + wave * 32 + (lane >> 2)) * N_ + (lane & 3) * 8;
  const unsigned short* bSt = Bm + (size_t)(c0 + wave * 32 + (lane >> 2)) * N_ + (lane & 3) * 8;
  const int ldsStW = wave * 1024;  // wave-uniform LDS dest within plane

  // fragment read bases (shorts)
  const int aRd = (wr * 128 + (lane & 15)) * 32 + (lane >> 4) * 8;
  const int bRd = (wc * 64  + (lane & 15)) * 32 + (lane >> 4) * 8;

  f32x4 acc[8][4] = {};
  bf16x8 afr[4], bfr[4];

#define STG(BASEG, LDSB, KT, KH) \
  gload16((BASEG) + (KT) * 64 + (KH) * 32, lds + (LDSB) + (KH) * 8192 + ldsStW); \
  gload16((BASEG) + (size_t)16 * N_ + (KT) * 64 + (KH) * 32, \
          lds + (LDSB) + (KH) * 8192 + ldsStW + 512);

#define RD_B(BUFB, KH) { \
  _Pragma("unroll") \
  for (int nf = 0; nf < 4; ++nf) \
    bfr[nf] = *(const bf16x8*)(lds + (BUFB) + (KH) * 8192 + nf * 512 + bRd); }

#define RD_A(BUFA, KH, QM) { \
  _Pragma("unroll") \
  for (int mm = 0; mm < 4; ++mm) \
    afr[mm] = *(const bf16x8*)(lds + (BUFA) + (KH) * 8192 + (QM) * 2048 + mm * 512 + aRd); }

#define MFMA16(QM) { \
  _Pragma("unroll") \
  for (int mm = 0; mm < 4; ++mm) \
  _Pragma("unroll") \
  for (int nf = 0; nf < 4; ++nf) \
    acc[(QM) * 4 + mm][nf] = __builtin_amdgcn_mfma_f32_16x16x32_bf16( \
        afr[mm], bfr[nf], acc[(QM) * 4 + mm][nf], 0, 0, 0); }

#define MIDBAR() \
  __builtin_amdgcn_s_barrier(); \
  asm volatile("s_waitcnt lgkmcnt(0)" ::: "memory"); \
  __builtin_amdgcn_sched_barrier(0); \
  __builtin_amdgcn_s_setprio(1);

#define ENDBAR() \
  __builtin_amdgcn_s_setprio(0); \
  __builtin_amdgcn_s_barrier();

#define WAITV(N) asm volatile("s_waitcnt vmcnt(" #N ")" ::: "memory");

  // ---- prologue: stage (0)kh0 A,B ; (0)kh1 A,B ; (1)kh0 A,B  (12 loads)
  STG(aSt, 0,     0, 0)  STG(bSt, 32768, 0, 0)
  STG(aSt, 0,     0, 1)  STG(bSt, 32768, 0, 1)
  STG(aSt, 16384, 1, 0)  STG(bSt, 49152, 1, 0)
  WAITV(8)                       // first 4 loads ((0)kh0 A+B) landed
  __builtin_amdgcn_s_barrier();

  // ---- main loop: iterations 0..14 (K-tiles 0..29), steady state
#pragma unroll 1
  for (int it = 0; it < 15; ++it) {
    const int kt0 = 2 * it;
    // gp0: compute buf0 kh0 qm0 ; stage A(2i+1)kh1 -> buf1.A
    RD_B(32768, 0) RD_A(0, 0, 0)
    STG(aSt, 16384, kt0 + 1, 1)
    MIDBAR() MFMA16(0) ENDBAR()
    // gp1: buf0 kh0 qm1 ; stage B(2i+1)kh1 ; wait
    RD_A(0, 0, 1)
    STG(bSt, 49152, kt0 + 1, 1)
    WAITV(8)
    MIDBAR() MFMA16(1) ENDBAR()
    // gp2: buf0 kh1 qm0 ; stage A(2i+2)kh0 -> buf0.A
    RD_B(32768, 1) RD_A(0, 1, 0)
    STG(aSt, 0, kt0 + 2, 0)
    MIDBAR() MFMA16(0) ENDBAR()
    // gp3: buf0 kh1 qm1 ; stage B(2i+2)kh0 ; wait
    RD_A(0, 1, 1)
    STG(bSt, 32768, kt0 + 2, 0)
    WAITV(8)
    MIDBAR() MFMA16(1) ENDBAR()
    // gp4: buf1 kh0 qm0 ; stage A(2i+2)kh1
    RD_B(49152, 0) RD_A(16384, 0, 0)
    STG(aSt, 0, kt0 + 2, 1)
    MIDBAR() MFMA16(0) ENDBAR()
    // gp5: buf1 kh0 qm1 ; stage B(2i+2)kh1 ; wait
    RD_A(16384, 0, 1)
    STG(bSt, 32768, kt0 + 2, 1)
    WAITV(8)
    MIDBAR() MFMA16(1) ENDBAR()
    // gp6: buf1 kh1 qm0 ; stage A(2i+3)kh0 -> buf1.A
    RD_B(49152, 1) RD_A(16384, 1, 0)
    STG(aSt, 16384, kt0 + 3, 0)
    MIDBAR() MFMA16(0) ENDBAR()
    // gp7: buf1 kh1 qm1 ; stage B(2i+3)kh0 ; wait
    RD_A(16384, 1, 1)
    STG(bSt, 49152, kt0 + 3, 0)
    WAITV(8)
    MIDBAR() MFMA16(1) ENDBAR()
  }

  // ---- tail iteration (K-tiles 30, 31): only (31)kh1 still to stage
  {
    RD_B(32768, 0) RD_A(0, 0, 0)
    STG(aSt, 16384, 31, 1)
    MIDBAR() MFMA16(0) ENDBAR()
    RD_A(0, 0, 1)
    STG(bSt, 49152, 31, 1)
    WAITV(8)
    MIDBAR() MFMA16(1) ENDBAR()
    RD_B(32768, 1) RD_A(0, 1, 0)
    MIDBAR() MFMA16(0) ENDBAR()
    RD_A(0, 1, 1)
    WAITV(4)
    MIDBAR() MFMA16(1) ENDBAR()
    RD_B(49152, 0) RD_A(16384, 0, 0)
    MIDBAR() MFMA16(0) ENDBAR()
    RD_A(16384, 0, 1)
    WAITV(0)
    MIDBAR() MFMA16(1) ENDBAR()
    RD_B(49152, 1) RD_A(16384, 1, 0)
    MIDBAR() MFMA16(0) ENDBAR()
    RD_A(16384, 1, 1)
    MIDBAR() MFMA16(1) ENDBAR()
  }

  // ---- epilogue. D frag: col(c) = lane&15, row(n) = (lane>>4)*4 + reg
  const int r4 = (lane >> 4) * 4;
  if (mode == 0) {
    float* outb = out + (size_t)b * CH * NT;
#pragma unroll
    for (int m = 0; m < 8; ++m) {
#pragma unroll
      for (int nf = 0; nf < 4; ++nf) {
        const int c = c0 + wc * 64 + nf * 16 + (lane & 15);
        const int o = c / 12;
        const int t = c - o * 12;
#pragma unroll
        for (int r = 0; r < 4; ++r) {
          const int n = n0 + wr * 128 + m * 16 + r4 + r;
          outb[((size_t)(ochan_base + o) * N_ + n) * T_ + t] = leaky(acc[m][nf][r]);
        }
      }
    }
  } else {
    unsigned short* Hb = Ht + (size_t)b * C_ * N_;
#pragma unroll
    for (int m = 0; m < 8; ++m) {
#pragma unroll
      for (int nf = 0; nf < 4; ++nf) {
        const int c = c0 + wc * 64 + nf * 16 + (lane & 15);
        const int nb = n0 + wr * 128 + m * 16 + r4;
        ushort4 u;
        u.x = f2bf(acc[m][nf][0]);
        u.y = f2bf(acc[m][nf][1]);
        u.z = f2bf(acc[m][nf][2]);
        u.w = f2bf(acc[m][nf][3]);
        *reinterpret_cast<ushort4*>(&Hb[(size_t)c * N_ + nb]) = u;
      }
    }
  }
#undef STG
#undef RD_B
#undef RD_A
#undef MFMA16
#undef MIDBAR
#undef ENDBAR
#undef WAITV
}

// ---------------------------------------------------------------------------
// Workspace layout (bytes):
//   adjb : [0, 67108864)                 8*2048*2048 bf16
//   G1   : [67108864, 92274688)          8*768*2048 bf16   (reused as Ht)
//   G2   : [92274688, 117440512)         8*768*2048 bf16
// ---------------------------------------------------------------------------
extern "C" void kernel_launch(void* const* d_in, const int* in_sizes, int n_in,
                              void* d_out, int out_size, void* d_ws, size_t ws_size,
                              hipStream_t stream) {
  const float* x   = (const float*)d_in[0];
  const float* adj = (const float*)d_in[1];
  const float* W0  = (const float*)d_in[2];
  const float* b0  = (const float*)d_in[3];
  const float* W1  = (const float*)d_in[4];
  const float* b1  = (const float*)d_in[5];
  const float* W2  = (const float*)d_in[6];
  const float* b2  = (const float*)d_in[7];
  float* out = (float*)d_out;

  char* ws = (char*)d_ws;
  unsigned short* adjb = (unsigned short*)ws;
  unsigned short* G1   = (unsigned short*)(ws + 67108864);
  unsigned short* G2   = (unsigned short*)(ws + 92274688);
  unsigned short* Ht   = G1;  // G1 dead after diffusion pass 1 -> reuse

  hipFuncSetAttribute((const void*)gemm8_k,
                      hipFuncAttributeMaxDynamicSharedMemorySize, 131072);

  // 1) adj -> bf16
  hipLaunchKernelGGL(convert_adj_k, dim3((B_ * N_ * N_ / 4) / 256), dim3(256), 0, stream,
                     adj, adjb);

  // 2) p=0: out channels [0,64) directly
  hipLaunchKernelGGL(p0_k, dim3(NT / 64, B_), dim3(256), 0, stream,
                     x, W0, b0, out);

  // 3) p=1,2 feature transforms -> G1, G2 (bf16, [c][m] layout)
  hipLaunchKernelGGL(p12_k, dim3(N_ / 16, B_), dim3(256), 0, stream,
                     x, W1, b1, W2, b2, G1, G2);

  // 4) diffusion p=1: out[64:128] = leaky(adj @ G1)
  hipLaunchKernelGGL(gemm8_k, dim3(192), dim3(512), 131072, stream,
                     adjb, G1, out, (unsigned short*)nullptr, 0, 64);

  // 5) diffusion p=2 hop 1: Ht = bf16(adj @ G2)
  hipLaunchKernelGGL(gemm8_k, dim3(192), dim3(512), 131072, stream,
                     adjb, G2, out, Ht, 1, 0);

  // 6) diffusion p=2 hop 2: out[128:192] = leaky(adj @ Ht)
  hipLaunchKernelGGL(gemm8_k, dim3(192), dim3(512), 131072, stream,
                     adjb, Ht, out, (unsigned short*)nullptr, 0, 128);
}

// Round 4
// 272.406 us; speedup vs baseline: 2.5792x; 1.0770x over previous
//
#include <hip/hip_runtime.h>

// Problem constants
#define B_ 8
#define N_ 2048
#define T_ 12
#define F_ 64
#define NT 24576    // N_*T_
#define CH 192      // 3 * 64 output channels
#define C_ 768      // 64 * 12 rows per diffusion GEMM B-operand

typedef __bf16 bf16x8 __attribute__((ext_vector_type(8)));
typedef float f32x4 __attribute__((ext_vector_type(4)));

typedef const __attribute__((address_space(1))) unsigned int as1_uint;
typedef __attribute__((address_space(3))) unsigned int as3_uint;

__device__ __forceinline__ void gload16(const void* g, void* l) {
  __builtin_amdgcn_global_load_lds((as1_uint*)g, (as3_uint*)l, 16, 0, 0);
}

__device__ __forceinline__ unsigned short f2bf(float f) {
  unsigned int u = __float_as_uint(f);
  u += 0x7FFFu + ((u >> 16) & 1u);   // RNE
  return (unsigned short)(u >> 16);
}

__device__ __forceinline__ float leaky(float v) {
  return v >= 0.0f ? v : 0.01f * v;
}

// ---------------------------------------------------------------------------
// adj fp32 -> bf16
// ---------------------------------------------------------------------------
__global__ __launch_bounds__(256) void convert_adj_k(const float* __restrict__ adj,
                                                     unsigned short* __restrict__ adjb) {
  size_t i = (size_t)blockIdx.x * 256 + threadIdx.x;
  const float4 v = reinterpret_cast<const float4*>(adj)[i];
  ushort4 u;
  u.x = f2bf(v.x); u.y = f2bf(v.y); u.z = f2bf(v.z); u.w = f2bf(v.w);
  reinterpret_cast<ushort4*>(adjb)[i] = u;
}

// ---------------------------------------------------------------------------
// Stage W^T (bf16, padded rows of 72) + bias into LDS. W is [64 f][64 o].
// ---------------------------------------------------------------------------
__device__ __forceinline__ void stage_wt(const float* __restrict__ W,
                                         unsigned short* Wt, int tid) {
  const int f = tid >> 2;
  const int q = tid & 3;
  const float4* row = reinterpret_cast<const float4*>(W + f * 64 + q * 16);
#pragma unroll
  for (int v4 = 0; v4 < 4; ++v4) {
    float4 v = row[v4];
    const int ob = q * 16 + v4 * 4;
    Wt[(ob + 0) * 72 + f] = f2bf(v.x);
    Wt[(ob + 1) * 72 + f] = f2bf(v.y);
    Wt[(ob + 2) * 72 + f] = f2bf(v.z);
    Wt[(ob + 3) * 72 + f] = f2bf(v.w);
  }
}

// ---------------------------------------------------------------------------
// p0_k: out[:, 0:64] = leaky(x . W0 + b0)   via MFMA, linear-e mapping.
// ---------------------------------------------------------------------------
__global__ __launch_bounds__(256) void p0_k(const float* __restrict__ x,
                                            const float* __restrict__ W0,
                                            const float* __restrict__ bia0,
                                            float* __restrict__ out) {
  __shared__ unsigned short Wt[64 * 72];
  __shared__ float bias[64];
  const int tid = threadIdx.x;
  stage_wt(W0, Wt, tid);
  if (tid < 64) bias[tid] = bia0[tid];
  __syncthreads();

  const int lane = tid & 63;
  const int wave = tid >> 6;
  const int b = blockIdx.y;
  const int e = blockIdx.x * 64 + wave * 16 + (lane & 15);
  const int fgrp = (lane >> 4) * 8;
  const float* xb = x + (size_t)b * F_ * NT;

  bf16x8 xf[2];
#pragma unroll
  for (int kf = 0; kf < 2; ++kf)
#pragma unroll
    for (int j = 0; j < 8; ++j)
      xf[kf][j] = (__bf16)xb[(size_t)(fgrp + kf * 32 + j) * NT + e];

  float* outb = out + (size_t)b * CH * NT;
#pragma unroll
  for (int ob = 0; ob < 4; ++ob) {
    f32x4 acc = {};
#pragma unroll
    for (int kf = 0; kf < 2; ++kf) {
      bf16x8 af = *reinterpret_cast<const bf16x8*>(
          &Wt[(ob * 16 + (lane & 15)) * 72 + kf * 32 + fgrp]);
      acc = __builtin_amdgcn_mfma_f32_16x16x32_bf16(af, xf[kf], acc, 0, 0, 0);
    }
#pragma unroll
    for (int r = 0; r < 4; ++r) {
      const int o = ob * 16 + (lane >> 4) * 4 + r;
      outb[(size_t)o * NT + e] = leaky(acc[r] + bias[o]);
    }
  }
}

// ---------------------------------------------------------------------------
// p12_k: G1 = x.W1 + b1, G2 = x.W2 + b2 (no activation), bf16 to
// G_p[(o*12+t)*N_ + n]  (K-contig for GEMM).
// ---------------------------------------------------------------------------
__global__ __launch_bounds__(256) void p12_k(const float* __restrict__ x,
                                             const float* __restrict__ W1,
                                             const float* __restrict__ bia1,
                                             const float* __restrict__ W2,
                                             const float* __restrict__ bia2,
                                             unsigned short* __restrict__ G1,
                                             unsigned short* __restrict__ G2) {
  __shared__ unsigned short Wt[2][64 * 72];
  __shared__ float bias[2][64];
  const int tid = threadIdx.x;
  stage_wt(W1, Wt[0], tid);
  stage_wt(W2, Wt[1], tid);
  if (tid < 64) bias[0][tid] = bia1[tid];
  else if (tid < 128) bias[1][tid - 64] = bia2[tid - 64];
  __syncthreads();

  const int lane = tid & 63;
  const int wave = tid >> 6;
  const int b = blockIdx.y;
  const int n = blockIdx.x * 16 + (lane & 15);
  const int fgrp = (lane >> 4) * 8;
  const float* xb = x + (size_t)b * F_ * NT;
  unsigned short* Gp[2] = {G1 + (size_t)b * C_ * N_, G2 + (size_t)b * C_ * N_};

#pragma unroll
  for (int it = 0; it < 3; ++it) {
    const int t = wave * 3 + it;
    const int e = n * T_ + t;

    bf16x8 xf[2];
#pragma unroll
    for (int kf = 0; kf < 2; ++kf)
#pragma unroll
      for (int j = 0; j < 8; ++j)
        xf[kf][j] = (__bf16)xb[(size_t)(fgrp + kf * 32 + j) * NT + e];

#pragma unroll
    for (int p = 0; p < 2; ++p) {
#pragma unroll
      for (int ob = 0; ob < 4; ++ob) {
        f32x4 acc = {};
#pragma unroll
        for (int kf = 0; kf < 2; ++kf) {
          bf16x8 af = *reinterpret_cast<const bf16x8*>(
              &Wt[p][(ob * 16 + (lane & 15)) * 72 + kf * 32 + fgrp]);
          acc = __builtin_amdgcn_mfma_f32_16x16x32_bf16(af, xf[kf], acc, 0, 0, 0);
        }
#pragma unroll
        for (int r = 0; r < 4; ++r) {
          const int o = ob * 16 + (lane >> 4) * 4 + r;
          Gp[p][(size_t)(o * T_ + t) * N_ + n] = f2bf(acc[r] + bias[p][o]);
        }
      }
    }
  }
}

// ---------------------------------------------------------------------------
// 256x192 8-phase diffusion GEMM (T2+T3+T4+T5), grid = 256 blocks = 1/CU.
// C[n][c] = sum_m adj[b][n][m] * Bt[b][c][m],  K = 2048, BK = 64.
// 512 threads = 8 waves (2 M x 4 N), per-wave output 128x48, acc[8][3].
//
// LDS 128KB, planes [2 kh][256 rows][32 shorts].  T2 conflict fix with ZERO
// inner-loop cost: LDS(r,c) holds global(r, c ^ ((r>>1)&3)) (granule = 16B).
//  - staging: linear gload_lds dest; per-lane GLOBAL source col pre-swizzled
//    by ((lane&3) ^ ((lane>>3)&3))  [involution; (r>>1)&3 == (lane>>3)&3 is
//    invariant across waves and both row-halves]
//  - reads: kg = (lane>>4) ^ ((lane>>1)&3) baked into aRd/bRd (all row bases
//    are multiples of 16 rows -> XOR term is lane-only).
// Per 8-lane beat every lane hits a distinct bank-quad -> conflict-free.
//
// B-plane keeps 256-row shape; rows 192..255 staged but unused (source row
// clamped to 767) so every wave issues identical load counts (vmcnt-uniform).
// Phase schedule + counted vmcnt(8) identical to round-3 template.
// grid 256 = 8 batches x (8 n-tiles x 4 c-tiles); blockIdx&7 = batch = XCD.
// ---------------------------------------------------------------------------
__global__ __launch_bounds__(512, 2) void gemm8_k(
    const unsigned short* __restrict__ adjb,
    const unsigned short* __restrict__ Bt,
    float* __restrict__ out,
    unsigned short* __restrict__ Ht,
    const int mode, const int ochan_base)
{
  extern __shared__ __align__(16) unsigned short lds[];  // 65536 shorts = 128KB
  // layout (shorts): A buf0 @0, A buf1 @16384, B buf0 @32768, B buf1 @49152
  // within buf: kh*8192 + row*32 + col

  const int tid  = threadIdx.x;
  const int lane = tid & 63;
  const int wave = tid >> 6;
  const int wr = wave >> 2;      // 0..1  (M half, 128 rows)
  const int wc = wave & 3;       // 0..3  (N quarter, 48 cols)

  const int b  = blockIdx.x & 7;            // batch == XCD (round-robin)
  const int w  = blockIdx.x >> 3;           // 0..31
  const int n0 = (w & 7) * 256;
  const int c0 = (w >> 3) * 192;

  const unsigned short* A  = adjb + (size_t)b * N_ * N_;
  const unsigned short* Bm = Bt   + (size_t)b * C_ * N_;

  // staging: lane covers row (wave*16 + lane>>2) [+128 for 2nd gload],
  // source col granule pre-swizzled.
  const int swzSrc = ((lane & 3) ^ ((lane >> 3) & 3)) * 8;   // shorts
  const unsigned short* aSt1 = A + (size_t)(n0 + wave * 16 + (lane >> 2)) * N_ + swzSrc;
  const unsigned short* aSt2 = aSt1 + (size_t)128 * N_;
  const unsigned short* bSt1 = Bm + (size_t)(c0 + wave * 16 + (lane >> 2)) * N_ + swzSrc;
  const int brow2 = c0 + 128 + wave * 16 + (lane >> 2);
  const unsigned short* bSt2 = Bm + (size_t)(brow2 < C_ ? brow2 : C_ - 1) * N_ + swzSrc;
  const int ldsW = wave * 512;   // shorts: wave's 16-row stripe within plane

  // fragment read bases (shorts), swizzled k-granule
  const int kg  = (lane >> 4) ^ ((lane >> 1) & 3);
  const int aRd = (wr * 128 + (lane & 15)) * 32 + kg * 8;
  const int bRd = (wc * 48  + (lane & 15)) * 32 + kg * 8;

  f32x4 acc[8][3] = {};
  bf16x8 afr[4], bfr[3];

#define STG(S1, S2, LDSB, KT, KH) \
  gload16((S1) + (KT) * 64 + (KH) * 32, lds + (LDSB) + (KH) * 8192 + ldsW); \
  gload16((S2) + (KT) * 64 + (KH) * 32, lds + (LDSB) + (KH) * 8192 + ldsW + 4096);

#define RD_B(BUFB, KH) { \
  _Pragma("unroll") \
  for (int nf = 0; nf < 3; ++nf) \
    bfr[nf] = *(const bf16x8*)(lds + (BUFB) + (KH) * 8192 + nf * 512 + bRd); }

#define RD_A(BUFA, KH, QM) { \
  _Pragma("unroll") \
  for (int mm = 0; mm < 4; ++mm) \
    afr[mm] = *(const bf16x8*)(lds + (BUFA) + (KH) * 8192 + (QM) * 2048 + mm * 512 + aRd); }

#define MFMA12(QM) { \
  _Pragma("unroll") \
  for (int mm = 0; mm < 4; ++mm) \
  _Pragma("unroll") \
  for (int nf = 0; nf < 3; ++nf) \
    acc[(QM) * 4 + mm][nf] = __builtin_amdgcn_mfma_f32_16x16x32_bf16( \
        afr[mm], bfr[nf], acc[(QM) * 4 + mm][nf], 0, 0, 0); }

#define MIDBAR() \
  __builtin_amdgcn_s_barrier(); \
  asm volatile("s_waitcnt lgkmcnt(0)" ::: "memory"); \
  __builtin_amdgcn_sched_barrier(0); \
  __builtin_amdgcn_s_setprio(1);

#define ENDBAR() \
  __builtin_amdgcn_s_setprio(0); \
  __builtin_amdgcn_s_barrier();

#define WAITV(N) asm volatile("s_waitcnt vmcnt(" #N ")" ::: "memory");

  // ---- prologue: stage (0)kh0 A,B ; (0)kh1 A,B ; (1)kh0 A,B  (12 loads)
  STG(aSt1, aSt2, 0,     0, 0)  STG(bSt1, bSt2, 32768, 0, 0)
  STG(aSt1, aSt2, 0,     0, 1)  STG(bSt1, bSt2, 32768, 0, 1)
  STG(aSt1, aSt2, 16384, 1, 0)  STG(bSt1, bSt2, 49152, 1, 0)
  WAITV(8)                       // first 4 loads ((0)kh0 A+B) landed
  __builtin_amdgcn_s_barrier();

  // ---- main loop: iterations 0..14 (K-tiles 0..29)
#pragma unroll 1
  for (int it = 0; it < 15; ++it) {
    const int kt0 = 2 * it;
    // gp0: compute buf0 kh0 qm0 ; stage A(2i+1)kh1 -> buf1.A
    RD_B(32768, 0) RD_A(0, 0, 0)
    STG(aSt1, aSt2, 16384, kt0 + 1, 1)
    MIDBAR() MFMA12(0) ENDBAR()
    // gp1: buf0 kh0 qm1 ; stage B(2i+1)kh1 ; wait
    RD_A(0, 0, 1)
    STG(bSt1, bSt2, 49152, kt0 + 1, 1)
    WAITV(8)
    MIDBAR() MFMA12(1) ENDBAR()
    // gp2: buf0 kh1 qm0 ; stage A(2i+2)kh0 -> buf0.A
    RD_B(32768, 1) RD_A(0, 1, 0)
    STG(aSt1, aSt2, 0, kt0 + 2, 0)
    MIDBAR() MFMA12(0) ENDBAR()
    // gp3: buf0 kh1 qm1 ; stage B(2i+2)kh0 ; wait
    RD_A(0, 1, 1)
    STG(bSt1, bSt2, 32768, kt0 + 2, 0)
    WAITV(8)
    MIDBAR() MFMA12(1) ENDBAR()
    // gp4: buf1 kh0 qm0 ; stage A(2i+2)kh1
    RD_B(49152, 0) RD_A(16384, 0, 0)
    STG(aSt1, aSt2, 0, kt0 + 2, 1)
    MIDBAR() MFMA12(0) ENDBAR()
    // gp5: buf1 kh0 qm1 ; stage B(2i+2)kh1 ; wait
    RD_A(16384, 0, 1)
    STG(bSt1, bSt2, 32768, kt0 + 2, 1)
    WAITV(8)
    MIDBAR() MFMA12(1) ENDBAR()
    // gp6: buf1 kh1 qm0 ; stage A(2i+3)kh0 -> buf1.A
    RD_B(49152, 1) RD_A(16384, 1, 0)
    STG(aSt1, aSt2, 16384, kt0 + 3, 0)
    MIDBAR() MFMA12(0) ENDBAR()
    // gp7: buf1 kh1 qm1 ; stage B(2i+3)kh0 ; wait
    RD_A(16384, 1, 1)
    STG(bSt1, bSt2, 49152, kt0 + 3, 0)
    WAITV(8)
    MIDBAR() MFMA12(1) ENDBAR()
  }

  // ---- tail iteration (K-tiles 30, 31): only (31)kh1 still to stage
  {
    RD_B(32768, 0) RD_A(0, 0, 0)
    STG(aSt1, aSt2, 16384, 31, 1)
    MIDBAR() MFMA12(0) ENDBAR()
    RD_A(0, 0, 1)
    STG(bSt1, bSt2, 49152, 31, 1)
    WAITV(8)
    MIDBAR() MFMA12(1) ENDBAR()
    RD_B(32768, 1) RD_A(0, 1, 0)
    MIDBAR() MFMA12(0) ENDBAR()
    RD_A(0, 1, 1)
    WAITV(4)
    MIDBAR() MFMA12(1) ENDBAR()
    RD_B(49152, 0) RD_A(16384, 0, 0)
    MIDBAR() MFMA12(0) ENDBAR()
    RD_A(16384, 0, 1)
    WAITV(0)
    MIDBAR() MFMA12(1) ENDBAR()
    RD_B(49152, 1) RD_A(16384, 1, 0)
    MIDBAR() MFMA12(0) ENDBAR()
    RD_A(16384, 1, 1)
    MIDBAR() MFMA12(1) ENDBAR()
  }

  // ---- epilogue. D frag: col(c) = lane&15, row(n) = (lane>>4)*4 + reg
  const int r4 = (lane >> 4) * 4;
  if (mode == 0) {
    float* outb = out + (size_t)b * CH * NT;
#pragma unroll
    for (int m = 0; m < 8; ++m) {
#pragma unroll
      for (int nf = 0; nf < 3; ++nf) {
        const int c = c0 + wc * 48 + nf * 16 + (lane & 15);
        const int o = c / 12;
        const int t = c - o * 12;
#pragma unroll
        for (int r = 0; r < 4; ++r) {
          const int n = n0 + wr * 128 + m * 16 + r4 + r;
          outb[((size_t)(ochan_base + o) * N_ + n) * T_ + t] = leaky(acc[m][nf][r]);
        }
      }
    }
  } else {
    unsigned short* Hb = Ht + (size_t)b * C_ * N_;
#pragma unroll
    for (int m = 0; m < 8; ++m) {
#pragma unroll
      for (int nf = 0; nf < 3; ++nf) {
        const int c = c0 + wc * 48 + nf * 16 + (lane & 15);
        const int nb = n0 + wr * 128 + m * 16 + r4;
        ushort4 u;
        u.x = f2bf(acc[m][nf][0]);
        u.y = f2bf(acc[m][nf][1]);
        u.z = f2bf(acc[m][nf][2]);
        u.w = f2bf(acc[m][nf][3]);
        *reinterpret_cast<ushort4*>(&Hb[(size_t)c * N_ + nb]) = u;
      }
    }
  }
#undef STG
#undef RD_B
#undef RD_A
#undef MFMA12
#undef MIDBAR
#undef ENDBAR
#undef WAITV
}

// ---------------------------------------------------------------------------
// Workspace layout (bytes):
//   adjb : [0, 67108864)                 8*2048*2048 bf16
//   G1   : [67108864, 92274688)          8*768*2048 bf16   (reused as Ht)
//   G2   : [92274688, 117440512)         8*768*2048 bf16
// ---------------------------------------------------------------------------
extern "C" void kernel_launch(void* const* d_in, const int* in_sizes, int n_in,
                              void* d_out, int out_size, void* d_ws, size_t ws_size,
                              hipStream_t stream) {
  const float* x   = (const float*)d_in[0];
  const float* adj = (const float*)d_in[1];
  const float* W0  = (const float*)d_in[2];
  const float* b0  = (const float*)d_in[3];
  const float* W1  = (const float*)d_in[4];
  const float* b1  = (const float*)d_in[5];
  const float* W2  = (const float*)d_in[6];
  const float* b2  = (const float*)d_in[7];
  float* out = (float*)d_out;

  char* ws = (char*)d_ws;
  unsigned short* adjb = (unsigned short*)ws;
  unsigned short* G1   = (unsigned short*)(ws + 67108864);
  unsigned short* G2   = (unsigned short*)(ws + 92274688);
  unsigned short* Ht   = G1;  // G1 dead after diffusion pass 1 -> reuse

  hipFuncSetAttribute((const void*)gemm8_k,
                      hipFuncAttributeMaxDynamicSharedMemorySize, 131072);

  // 1) adj -> bf16
  hipLaunchKernelGGL(convert_adj_k, dim3((B_ * N_ * N_ / 4) / 256), dim3(256), 0, stream,
                     adj, adjb);

  // 2) p=0: out channels [0,64) directly
  hipLaunchKernelGGL(p0_k, dim3(NT / 64, B_), dim3(256), 0, stream,
                     x, W0, b0, out);

  // 3) p=1,2 feature transforms -> G1, G2 (bf16, [c][m] layout)
  hipLaunchKernelGGL(p12_k, dim3(N_ / 16, B_), dim3(256), 0, stream,
                     x, W1, b1, W2, b2, G1, G2);

  // 4) diffusion p=1: out[64:128] = leaky(adj @ G1)
  hipLaunchKernelGGL(gemm8_k, dim3(256), dim3(512), 131072, stream,
                     adjb, G1, out, (unsigned short*)nullptr, 0, 64);

  // 5) diffusion p=2 hop 1: Ht = bf16(adj @ G2)
  hipLaunchKernelGGL(gemm8_k, dim3(256), dim3(512), 131072, stream,
                     adjb, G2, out, Ht, 1, 0);

  // 6) diffusion p=2 hop 2: out[128:192] = leaky(adj @ Ht)
  hipLaunchKernelGGL(gemm8_k, dim3(256), dim3(512), 131072, stream,
                     adjb, Ht, out, (unsigned short*)nullptr, 0, 128);
}